// Round 2
// baseline (53.240 us; speedup 1.0000x reference)
//
#include <hip/hip_runtime.h>
#include <math.h>

namespace {
constexpr int   NTYPES   = 200;
constexpr float CONST_T  = 0.89776110649108887f; // exp(-0.004314*(298-273))
constexpr float RAD10_   = 0.17453292519943295f;
constexpr float RAD30_   = 0.52359877559829882f;
constexpr float RAD150_  = 2.6179938779914944f;
constexpr float RAD180_  = 3.14159265358979323f;
constexpr float ION_CORR = 0.02f + 0.05f / 1.4f;

// bit layout of packed word (rec.w):
//  0..7  at_name (0..199)
//  8..9  chain
// 10..18 resnum (0..499)
// 19     rc (at==10 | at==11)
// 20     cz (at==12)
// 21     aa (at==13)
// 22     charged (props[at][0]==1)
// 23     virtual (props[at][2]==1)
// 24     dipole0 (props[at][3]==0)
constexpr unsigned RC_B   = 1u << 19;
constexpr unsigned CZ_B   = 1u << 20;
constexpr unsigned AA_B   = 1u << 21;
constexpr unsigned CHG_B  = 1u << 22;
constexpr unsigned VIRT_B = 1u << 23;
constexpr unsigned DIP0_B = 1u << 24;
constexpr unsigned RESCH_M = 0x7FF00u;  // chain(8..9) | resnum(10..18)
constexpr unsigned CHAIN_M = 0x300u;
}

__global__ __launch_bounds__(256) void prep_kernel(
    const float* __restrict__ coords,
    const float* __restrict__ props,
    const int*   __restrict__ desc,
    float4*      __restrict__ rec,
    int natoms)
{
    const int idx = blockIdx.x * blockDim.x + threadIdx.x;
    if (idx >= natoms) return;
    const int at  = desc[3 * idx];
    const int res = desc[3 * idx + 1];
    const int ch  = desc[3 * idx + 2];
    unsigned bits = (unsigned)at | ((unsigned)ch << 8) | ((unsigned)res << 10);
    if ((at == 10) | (at == 11))       bits |= RC_B;
    if (at == 12)                      bits |= CZ_B;
    if (at == 13)                      bits |= AA_B;
    if (props[5 * at + 0] == 1.0f)     bits |= CHG_B;
    if (props[5 * at + 2] == 1.0f)     bits |= VIRT_B;
    if (props[5 * at + 3] == 0.0f)     bits |= DIP0_B;
    rec[idx] = make_float4(coords[3 * idx], coords[3 * idx + 1], coords[3 * idx + 2],
                           __uint_as_float(bits));
}

__device__ __forceinline__ float pair_energy(
    const float4 A, const float4 B, int i, int j,
    const float* __restrict__ partners, const float2* __restrict__ cr)
{
    const unsigned ba = __float_as_uint(A.w);
    const unsigned bb = __float_as_uint(B.w);

    const bool czA = (ba & CZ_B) != 0, czB = (bb & CZ_B) != 0;
    const bool rcA = (ba & RC_B) != 0, rcB = (bb & RC_B) != 0;
    const bool argInv = (czA & (czB | rcB)) | (czB & (czA | rcA));
    const bool is_charged = ((ba & bb & CHG_B) != 0) | argInv;
    if (!is_charged) return 0.0f;

    const float dx = A.x - B.x, dy = A.y - B.y, dz = A.z - B.z;
    const float dist = sqrtf(dx * dx + dy * dy + dz * dz + 1e-12f);
    const bool diff_res = ((ba ^ bb) & RESCH_M) != 0;
    if (!((dist <= 15.0f) & diff_res)) return 0.0f;

    float energy = 0.0f;

    // ---- ARG path (extremely rare): needs partners[] ----
    if (argInv && (dist >= 3.9f) && (dist <= 4.3f)) {
        const float a0x = partners[6 * i],     a0y = partners[6 * i + 1], a0z = partners[6 * i + 2];
        const float a1x = partners[6 * i + 3], a1y = partners[6 * i + 4], a1z = partners[6 * i + 5];
        const float b0x = partners[6 * j],     b0y = partners[6 * j + 1], b0z = partners[6 * j + 2];
        const float b1x = partners[6 * j + 3], b1y = partners[6 * j + 4], b1z = partners[6 * j + 5];
        const float u1x = a0x - A.x, u1y = a0y - A.y, u1z = a0z - A.z;
        const float v1x = a1x - A.x, v1y = a1y - A.y, v1z = a1z - A.z;
        const float n1x = u1y * v1z - u1z * v1y;
        const float n1y = u1z * v1x - u1x * v1z;
        const float n1z = u1x * v1y - u1y * v1x;
        const float u2x = b0x - B.x, u2y = b0y - B.y, u2z = b0z - B.z;
        const float v2x = b1x - B.x, v2y = b1y - B.y, v2z = b1z - B.z;
        const float n2x = u2y * v2z - u2z * v2y;
        const float n2y = u2z * v2x - u2x * v2z;
        const float n2z = u2x * v2y - u2y * v2x;
        const float nn1 = sqrtf(n1x * n1x + n1y * n1y + n1z * n1z + 1e-12f);
        const float nn2 = sqrtf(n2x * n2x + n2y * n2y + n2z * n2z + 1e-12f);
        const bool  m = (nn1 > 1e-6f) & (nn2 > 1e-6f);
        float cosang = (n1x * n2x + n1y * n2y + n1z * n2z) / (nn1 * nn2);
        cosang = fminf(fmaxf(cosang, -0.999999f), 0.999999f);
        const float ang = acosf(cosang);
        const bool ang_mid_bad = (ang > RAD30_) & (ang < RAD150_);
        if (m & !ang_mid_bad) {
            const float dsafe   = fmaxf(dist, 1e-6f);
            const float argEpss = 332.0f / (dsafe * 8.8f * CONST_T);
            const float temp_d  = 3.0f + fabsf(dist - 4.1f);
            const float corr_ang = (dist > RAD150_)   // reference quirk: dist vs RAD150
                ? fmaxf((RAD180_ - ang) / RAD10_, 1.0f)
                : fmaxf(dist / RAD10_, 1.0f);
            const bool  arg_arg = ((ba & bb & AA_B) != 0);
            const float c2e = arg_arg ? -1.0f : -0.5f;
            const float vk  = sqrtf(200.0f * fabsf(c2e) * ION_CORR / 298.0f);
            energy += (1.0f / corr_ang) * c2e * argEpss *
                      expf(-temp_d * vk) / (temp_d * temp_d);
        }
    }

    // ---- kon path ----
    const float2 t1 = cr[ba & 255u];
    const float2 t2 = cr[bb & 255u];
    const float c1 = t1.x, c2 = t2.x;
    const bool charged_charged =
        (c1 != 0.0f) & (c2 != 0.0f) &
        ((ba & VIRT_B) == 0) & ((bb & VIRT_B) == 0);
    const bool kon_mask = charged_charged &
        ((ba & DIP0_B) != 0) & ((bb & DIP0_B) != 0) &
        (((ba ^ bb) & CHAIN_M) != 0);
    if (kon_mask) {
        const float sum_radii = t1.y + t2.y - 0.09f;
        const float dd   = fmaxf(dist, sum_radii);
        const float tk   = fmaxf(dd + dd * dd * (1.0f / 30.0f), 6.0f);
        const float k_on = sqrtf(200.0f * fabsf(c1) * fabsf(c2) * 0.05f / 298.0f);
        const float first  = 332.0f * c1 * c2 / (88.0f * tk * CONST_T);
        const float second = expf(-k_on * (tk - 6.0f));
        const float third  = 1.0f + k_on * 6.0f;
        energy += 0.5f * first * second / third;
    }
    return energy;
}

template <int PPT>
__global__ __launch_bounds__(256) void electro_kernel2(
    const float4* __restrict__ rec,
    const float*  __restrict__ partners,
    const float*  __restrict__ props,
    const int2*   __restrict__ pairs,
    float*        __restrict__ out,
    int n)
{
    __shared__ float2 cr[NTYPES];   // (charge, radius) per type
    for (int t = threadIdx.x; t < NTYPES; t += blockDim.x)
        cr[t] = make_float2(props[5 * t + 1], props[5 * t + 4]);
    __syncthreads();

    const int base = blockIdx.x * blockDim.x * PPT + threadIdx.x;

    int2   pr[PPT];
    float4 A[PPT], B[PPT];
    bool   ok[PPT];
#pragma unroll
    for (int k = 0; k < PPT; ++k) {
        const int p = base + k * 256;
        ok[k] = (p < n);
        pr[k] = ok[k] ? pairs[p] : make_int2(0, 0);
    }
#pragma unroll
    for (int k = 0; k < PPT; ++k) {
        A[k] = rec[pr[k].x];
        B[k] = rec[pr[k].y];
    }
#pragma unroll
    for (int k = 0; k < PPT; ++k) {
        if (ok[k]) {
            out[base + k * 256] =
                pair_energy(A[k], B[k], pr[k].x, pr[k].y, partners, cr);
        }
    }
}

// -------- fallback (round-1 kernel) used only if d_ws is too small --------
__global__ __launch_bounds__(256) void electro_fallback(
    const float* __restrict__ coords, const float* __restrict__ partners,
    const float* __restrict__ props, const int* __restrict__ desc,
    const int2* __restrict__ pairs, float* __restrict__ out, int n)
{
    __shared__ float sp[NTYPES * 5];
    for (int t = threadIdx.x; t < NTYPES * 5; t += blockDim.x) sp[t] = props[t];
    __syncthreads();
    const int stride = gridDim.x * blockDim.x;
    for (int p = blockIdx.x * blockDim.x + threadIdx.x; p < n; p += stride) {
        const int2 ij = pairs[p];
        const int i = ij.x, j = ij.y;
        const int at1 = desc[3 * i], at2 = desc[3 * j];
        const bool rc1 = (at1 == 10) | (at1 == 11);
        const bool rc2 = (at2 == 10) | (at2 == 11);
        const bool argInv = ((at1 == 12) & ((at2 == 12) | rc2)) |
                            ((at2 == 12) & ((at1 == 12) | rc1));
        const float* p1 = &sp[5 * at1];
        const float* p2 = &sp[5 * at2];
        const bool is_charged = ((p1[0] == 1.0f) & (p2[0] == 1.0f)) | argInv;
        float energy = 0.0f;
        if (is_charged) {
            const int res1 = desc[3 * i + 1], ch1 = desc[3 * i + 2];
            const int res2 = desc[3 * j + 1], ch2 = desc[3 * j + 2];
            const float ax = coords[3 * i], ay = coords[3 * i + 1], az = coords[3 * i + 2];
            const float bx = coords[3 * j], by = coords[3 * j + 1], bz = coords[3 * j + 2];
            const float dx = ax - bx, dy = ay - by, dz = az - bz;
            const float dist = sqrtf(dx * dx + dy * dy + dz * dz + 1e-12f);
            const bool diff_res = (res1 != res2) | (ch1 != ch2);
            if ((dist <= 15.0f) & diff_res) {
                if (argInv && (dist >= 3.9f) && (dist <= 4.3f)) {
                    const float a0x = partners[6*i],   a0y = partners[6*i+1], a0z = partners[6*i+2];
                    const float a1x = partners[6*i+3], a1y = partners[6*i+4], a1z = partners[6*i+5];
                    const float b0x = partners[6*j],   b0y = partners[6*j+1], b0z = partners[6*j+2];
                    const float b1x = partners[6*j+3], b1y = partners[6*j+4], b1z = partners[6*j+5];
                    const float u1x=a0x-ax,u1y=a0y-ay,u1z=a0z-az;
                    const float v1x=a1x-ax,v1y=a1y-ay,v1z=a1z-az;
                    const float n1x=u1y*v1z-u1z*v1y, n1y=u1z*v1x-u1x*v1z, n1z=u1x*v1y-u1y*v1x;
                    const float u2x=b0x-bx,u2y=b0y-by,u2z=b0z-bz;
                    const float v2x=b1x-bx,v2y=b1y-by,v2z=b1z-bz;
                    const float n2x=u2y*v2z-u2z*v2y, n2y=u2z*v2x-u2x*v2z, n2z=u2x*v2y-u2y*v2x;
                    const float nn1 = sqrtf(n1x*n1x+n1y*n1y+n1z*n1z+1e-12f);
                    const float nn2 = sqrtf(n2x*n2x+n2y*n2y+n2z*n2z+1e-12f);
                    const bool m = (nn1 > 1e-6f) & (nn2 > 1e-6f);
                    float cosang = (n1x*n2x+n1y*n2y+n1z*n2z)/(nn1*nn2);
                    cosang = fminf(fmaxf(cosang, -0.999999f), 0.999999f);
                    const float ang = acosf(cosang);
                    const bool ang_mid_bad = (ang > RAD30_) & (ang < RAD150_);
                    if (m & !ang_mid_bad) {
                        const float dsafe = fmaxf(dist, 1e-6f);
                        const float argEpss = 332.0f / (dsafe * 8.8f * CONST_T);
                        const float temp_d = 3.0f + fabsf(dist - 4.1f);
                        const float corr_ang = (dist > RAD150_)
                            ? fmaxf((RAD180_ - ang) / RAD10_, 1.0f)
                            : fmaxf(dist / RAD10_, 1.0f);
                        const bool arg_arg = (at1 == 13) & (at2 == 13);
                        const float c2e = arg_arg ? -1.0f : -0.5f;
                        const float vk = sqrtf(200.0f * fabsf(c2e) * ION_CORR / 298.0f);
                        energy += (1.0f/corr_ang)*c2e*argEpss*expf(-temp_d*vk)/(temp_d*temp_d);
                    }
                }
                const float c1 = p1[1], c2 = p2[1];
                const bool cc = (c1 != 0.0f) & (c2 != 0.0f) &
                                (p1[2] != 1.0f) & (p2[2] != 1.0f);
                const bool kon_mask = cc & (p1[3] == 0.0f) & (p2[3] == 0.0f) & (ch1 != ch2);
                if (kon_mask) {
                    const float sum_radii = p1[4] + p2[4] - 0.09f;
                    const float dd = fmaxf(dist, sum_radii);
                    const float tk = fmaxf(dd + dd*dd*(1.0f/30.0f), 6.0f);
                    const float k_on = sqrtf(200.0f*fabsf(c1)*fabsf(c2)*0.05f/298.0f);
                    const float first = 332.0f*c1*c2/(88.0f*tk*CONST_T);
                    const float second = expf(-k_on*(tk-6.0f));
                    const float third = 1.0f + k_on*6.0f;
                    energy += 0.5f*first*second/third;
                }
            }
        }
        out[p] = energy;
    }
}

extern "C" void kernel_launch(void* const* d_in, const int* in_sizes, int n_in,
                              void* d_out, int out_size, void* d_ws, size_t ws_size,
                              hipStream_t stream) {
    const float* coords   = (const float*)d_in[0];
    const float* partners = (const float*)d_in[1];
    const float* props    = (const float*)d_in[2];
    const int*   desc     = (const int*)d_in[3];
    const int2*  pairs    = (const int2*)d_in[4];
    float*       out      = (float*)d_out;

    const int natoms = in_sizes[0] / 3;   // 100,000
    const int n      = in_sizes[4] / 2;   // 4,000,000 pairs

    const size_t rec_bytes = (size_t)natoms * sizeof(float4);
    if (ws_size >= rec_bytes) {
        float4* rec = (float4*)d_ws;
        prep_kernel<<<(natoms + 255) / 256, 256, 0, stream>>>(coords, props, desc, rec, natoms);
        constexpr int PPT = 4;
        const int grid = (n + 256 * PPT - 1) / (256 * PPT);
        electro_kernel2<PPT><<<grid, 256, 0, stream>>>(rec, partners, props, pairs, out, n);
    } else {
        const int block = 256;
        int grid = (n + block - 1) / block;
        if (grid > 2048) grid = 2048;
        electro_fallback<<<grid, block, 0, stream>>>(coords, partners, props, desc, pairs, out, n);
    }
}

// Round 3
// 48.088 us; speedup vs baseline: 1.1071x; 1.1071x over previous
//
#include <hip/hip_runtime.h>
#include <math.h>

namespace {
constexpr int   NTYPES   = 200;
constexpr float CONST_T  = 0.89776110649108887f; // exp(-0.004314*(298-273))
constexpr float RAD10_   = 0.17453292519943295f;
constexpr float RAD30_   = 0.52359877559829882f;
constexpr float RAD150_  = 2.6179938779914944f;
constexpr float RAD180_  = 3.14159265358979323f;
constexpr float ION_CORR = 0.02f + 0.05f / 1.4f;

// rec.w bit layout:
//  0..7  at_name, 8..9 chain, 10..18 resnum,
// 19 rc, 20 cz, 21 aa, 22 charged, 23 virtual, 24 dipole0
constexpr unsigned RC_B   = 1u << 19;
constexpr unsigned CZ_B   = 1u << 20;
constexpr unsigned AA_B   = 1u << 21;
constexpr unsigned CHG_B  = 1u << 22;
constexpr unsigned VIRT_B = 1u << 23;
constexpr unsigned DIP0_B = 1u << 24;
constexpr unsigned RESCH_M = 0x7FF00u;  // chain | resnum
constexpr unsigned CHAIN_M = 0x300u;

// filter nibble bits (4 bits/atom, 8 atoms/u32): 1=charged, 2=cz, 4=rc
}

__global__ __launch_bounds__(256) void prep_rec(
    const float* __restrict__ coords,
    const float* __restrict__ props,
    const int*   __restrict__ desc,
    float4*      __restrict__ rec,
    int natoms)
{
    const int idx = blockIdx.x * blockDim.x + threadIdx.x;
    if (idx >= natoms) return;
    const int at  = desc[3 * idx];
    const int res = desc[3 * idx + 1];
    const int ch  = desc[3 * idx + 2];
    unsigned bits = (unsigned)at | ((unsigned)ch << 8) | ((unsigned)res << 10);
    if ((at == 10) | (at == 11))       bits |= RC_B;
    if (at == 12)                      bits |= CZ_B;
    if (at == 13)                      bits |= AA_B;
    if (props[5 * at + 0] == 1.0f)     bits |= CHG_B;
    if (props[5 * at + 2] == 1.0f)     bits |= VIRT_B;
    if (props[5 * at + 3] == 0.0f)     bits |= DIP0_B;
    rec[idx] = make_float4(coords[3 * idx], coords[3 * idx + 1], coords[3 * idx + 2],
                           __uint_as_float(bits));
}

__global__ __launch_bounds__(256) void prep_filt(
    const float* __restrict__ props,
    const int*   __restrict__ desc,
    unsigned*    __restrict__ filt,
    int nwords, int natoms)
{
    const int w = blockIdx.x * blockDim.x + threadIdx.x;
    if (w >= nwords) return;
    unsigned word = 0;
    for (int s = 0; s < 8; ++s) {
        const int a = w * 8 + s;
        if (a < natoms) {
            const int at = desc[3 * a];
            unsigned nib = 0;
            if (props[5 * at] == 1.0f)     nib |= 1u;
            if (at == 12)                  nib |= 2u;
            if ((at == 10) | (at == 11))   nib |= 4u;
            word |= nib << (s * 4);
        }
    }
    filt[w] = word;
}

__device__ __forceinline__ float pair_energy(
    const float4 A, const float4 B, int i, int j,
    const float* __restrict__ partners, const float2* __restrict__ cr)
{
    const unsigned ba = __float_as_uint(A.w);
    const unsigned bb = __float_as_uint(B.w);

    const bool czA = (ba & CZ_B) != 0, czB = (bb & CZ_B) != 0;
    const bool rcA = (ba & RC_B) != 0, rcB = (bb & RC_B) != 0;
    const bool argInv = (czA & (czB | rcB)) | (czB & (czA | rcA));

    const float dx = A.x - B.x, dy = A.y - B.y, dz = A.z - B.z;
    const float dist = sqrtf(dx * dx + dy * dy + dz * dz + 1e-12f);
    const bool diff_res = ((ba ^ bb) & RESCH_M) != 0;
    if (!((dist <= 15.0f) & diff_res)) return 0.0f;

    float energy = 0.0f;

    // ---- ARG path (extremely rare): needs partners[] ----
    if (argInv && (dist >= 3.9f) && (dist <= 4.3f)) {
        const float a0x = partners[6 * i],     a0y = partners[6 * i + 1], a0z = partners[6 * i + 2];
        const float a1x = partners[6 * i + 3], a1y = partners[6 * i + 4], a1z = partners[6 * i + 5];
        const float b0x = partners[6 * j],     b0y = partners[6 * j + 1], b0z = partners[6 * j + 2];
        const float b1x = partners[6 * j + 3], b1y = partners[6 * j + 4], b1z = partners[6 * j + 5];
        const float u1x = a0x - A.x, u1y = a0y - A.y, u1z = a0z - A.z;
        const float v1x = a1x - A.x, v1y = a1y - A.y, v1z = a1z - A.z;
        const float n1x = u1y * v1z - u1z * v1y;
        const float n1y = u1z * v1x - u1x * v1z;
        const float n1z = u1x * v1y - u1y * v1x;
        const float u2x = b0x - B.x, u2y = b0y - B.y, u2z = b0z - B.z;
        const float v2x = b1x - B.x, v2y = b1y - B.y, v2z = b1z - B.z;
        const float n2x = u2y * v2z - u2z * v2y;
        const float n2y = u2z * v2x - u2x * v2z;
        const float n2z = u2x * v2y - u2y * v2x;
        const float nn1 = sqrtf(n1x * n1x + n1y * n1y + n1z * n1z + 1e-12f);
        const float nn2 = sqrtf(n2x * n2x + n2y * n2y + n2z * n2z + 1e-12f);
        const bool  m = (nn1 > 1e-6f) & (nn2 > 1e-6f);
        float cosang = (n1x * n2x + n1y * n2y + n1z * n2z) / (nn1 * nn2);
        cosang = fminf(fmaxf(cosang, -0.999999f), 0.999999f);
        const float ang = acosf(cosang);
        const bool ang_mid_bad = (ang > RAD30_) & (ang < RAD150_);
        if (m & !ang_mid_bad) {
            const float dsafe   = fmaxf(dist, 1e-6f);
            const float argEpss = 332.0f / (dsafe * 8.8f * CONST_T);
            const float temp_d  = 3.0f + fabsf(dist - 4.1f);
            const float corr_ang = (dist > RAD150_)   // reference quirk: dist vs RAD150
                ? fmaxf((RAD180_ - ang) / RAD10_, 1.0f)
                : fmaxf(dist / RAD10_, 1.0f);
            const bool  arg_arg = ((ba & bb & AA_B) != 0);
            const float c2e = arg_arg ? -1.0f : -0.5f;
            const float vk  = sqrtf(200.0f * fabsf(c2e) * ION_CORR / 298.0f);
            energy += (1.0f / corr_ang) * c2e * argEpss *
                      expf(-temp_d * vk) / (temp_d * temp_d);
        }
    }

    // ---- kon path ----
    const float2 t1 = cr[ba & 255u];
    const float2 t2 = cr[bb & 255u];
    const float c1 = t1.x, c2 = t2.x;
    const bool charged_charged =
        (c1 != 0.0f) & (c2 != 0.0f) &
        ((ba & VIRT_B) == 0) & ((bb & VIRT_B) == 0);
    const bool kon_mask = charged_charged &
        ((ba & DIP0_B) != 0) & ((bb & DIP0_B) != 0) &
        (((ba ^ bb) & CHAIN_M) != 0);
    if (kon_mask) {
        const float sum_radii = t1.y + t2.y - 0.09f;
        const float dd   = fmaxf(dist, sum_radii);
        const float tk   = fmaxf(dd + dd * dd * (1.0f / 30.0f), 6.0f);
        const float k_on = sqrtf(200.0f * fabsf(c1) * fabsf(c2) * 0.05f / 298.0f);
        const float first  = 332.0f * c1 * c2 / (88.0f * tk * CONST_T);
        const float second = expf(-k_on * (tk - 6.0f));
        const float third  = 1.0f + k_on * 6.0f;
        energy += 0.5f * first * second / third;
    }
    return energy;
}

template <int PPT>
__global__ __launch_bounds__(256) void electro_kernel3(
    const float4*   __restrict__ rec,       // [natoms] L2-resident, hot pairs only
    const unsigned* __restrict__ filt,      // [natoms/8] 50 KB, L1-hot
    const float*    __restrict__ partners,
    const float*    __restrict__ props,
    const int2*     __restrict__ pairs,
    float*          __restrict__ out,
    int n)
{
    __shared__ float2 cr[NTYPES];   // (charge, radius) per type
    for (int t = threadIdx.x; t < NTYPES; t += blockDim.x)
        cr[t] = make_float2(props[5 * t + 1], props[5 * t + 4]);
    __syncthreads();

    const int base = blockIdx.x * (blockDim.x * PPT) + threadIdx.x;

    int  ii[PPT], jj[PPT];
    bool ok[PPT];
#pragma unroll
    for (int k = 0; k < PPT; ++k) {
        const int p = base + k * 256;
        ok[k] = (p < n);
        // nontemporal: pairs stream is read-once, keep it out of L2
        unsigned long long v = ok[k]
            ? __builtin_nontemporal_load((const unsigned long long*)(pairs + p))
            : 0ull;
        ii[k] = (int)(v & 0xffffffffu);
        jj[k] = (int)(v >> 32);
    }

    unsigned f1[PPT], f2[PPT];
#pragma unroll
    for (int k = 0; k < PPT; ++k) {
        f1[k] = filt[ii[k] >> 3];      // 50 KB table: L1-hot dword gathers
        f2[k] = filt[jj[k] >> 3];
    }

#pragma unroll
    for (int k = 0; k < PPT; ++k) {
        const unsigned n1 = (f1[k] >> ((ii[k] & 7) * 4)) & 0xFu;
        const unsigned n2 = (f2[k] >> ((jj[k] & 7) * 4)) & 0xFu;
        const bool cz1 = (n1 & 2u) != 0, cz2 = (n2 & 2u) != 0;
        const bool argInv = (cz1 & ((n2 & 6u) != 0)) | (cz2 & ((n1 & 6u) != 0));
        const bool is_ch  = ((n1 & n2 & 1u) != 0) | argInv;
        float e = 0.0f;
        if (is_ch) {   // ~16% of lanes: only they issue the 16B rec gathers
            const float4 A = rec[ii[k]];
            const float4 B = rec[jj[k]];
            e = pair_energy(A, B, ii[k], jj[k], partners, cr);
        }
        if (ok[k]) __builtin_nontemporal_store(e, &out[base + k * 256]);
    }
}

// -------- fallback (round-1 kernel) used only if d_ws is too small --------
__global__ __launch_bounds__(256) void electro_fallback(
    const float* __restrict__ coords, const float* __restrict__ partners,
    const float* __restrict__ props, const int* __restrict__ desc,
    const int2* __restrict__ pairs, float* __restrict__ out, int n)
{
    __shared__ float sp[NTYPES * 5];
    for (int t = threadIdx.x; t < NTYPES * 5; t += blockDim.x) sp[t] = props[t];
    __syncthreads();
    const int stride = gridDim.x * blockDim.x;
    for (int p = blockIdx.x * blockDim.x + threadIdx.x; p < n; p += stride) {
        const int2 ij = pairs[p];
        const int i = ij.x, j = ij.y;
        const int at1 = desc[3 * i], at2 = desc[3 * j];
        const bool rc1 = (at1 == 10) | (at1 == 11);
        const bool rc2 = (at2 == 10) | (at2 == 11);
        const bool argInv = ((at1 == 12) & ((at2 == 12) | rc2)) |
                            ((at2 == 12) & ((at1 == 12) | rc1));
        const float* p1 = &sp[5 * at1];
        const float* p2 = &sp[5 * at2];
        const bool is_charged = ((p1[0] == 1.0f) & (p2[0] == 1.0f)) | argInv;
        float energy = 0.0f;
        if (is_charged) {
            const int res1 = desc[3 * i + 1], ch1 = desc[3 * i + 2];
            const int res2 = desc[3 * j + 1], ch2 = desc[3 * j + 2];
            const float ax = coords[3 * i], ay = coords[3 * i + 1], az = coords[3 * i + 2];
            const float bx = coords[3 * j], by = coords[3 * j + 1], bz = coords[3 * j + 2];
            const float dx = ax - bx, dy = ay - by, dz = az - bz;
            const float dist = sqrtf(dx * dx + dy * dy + dz * dz + 1e-12f);
            const bool diff_res = (res1 != res2) | (ch1 != ch2);
            if ((dist <= 15.0f) & diff_res) {
                if (argInv && (dist >= 3.9f) && (dist <= 4.3f)) {
                    const float a0x = partners[6*i],   a0y = partners[6*i+1], a0z = partners[6*i+2];
                    const float a1x = partners[6*i+3], a1y = partners[6*i+4], a1z = partners[6*i+5];
                    const float b0x = partners[6*j],   b0y = partners[6*j+1], b0z = partners[6*j+2];
                    const float b1x = partners[6*j+3], b1y = partners[6*j+4], b1z = partners[6*j+5];
                    const float u1x=a0x-ax,u1y=a0y-ay,u1z=a0z-az;
                    const float v1x=a1x-ax,v1y=a1y-ay,v1z=a1z-az;
                    const float n1x=u1y*v1z-u1z*v1y, n1y=u1z*v1x-u1x*v1z, n1z=u1x*v1y-u1y*v1x;
                    const float u2x=b0x-bx,u2y=b0y-by,u2z=b0z-bz;
                    const float v2x=b1x-bx,v2y=b1y-by,v2z=b1z-bz;
                    const float n2x=u2y*v2z-u2z*v2y, n2y=u2z*v2x-u2x*v2z, n2z=u2x*v2y-u2y*v2x;
                    const float nn1 = sqrtf(n1x*n1x+n1y*n1y+n1z*n1z+1e-12f);
                    const float nn2 = sqrtf(n2x*n2x+n2y*n2y+n2z*n2z+1e-12f);
                    const bool m = (nn1 > 1e-6f) & (nn2 > 1e-6f);
                    float cosang = (n1x*n2x+n1y*n2y+n1z*n2z)/(nn1*nn2);
                    cosang = fminf(fmaxf(cosang, -0.999999f), 0.999999f);
                    const float ang = acosf(cosang);
                    const bool ang_mid_bad = (ang > RAD30_) & (ang < RAD150_);
                    if (m & !ang_mid_bad) {
                        const float dsafe = fmaxf(dist, 1e-6f);
                        const float argEpss = 332.0f / (dsafe * 8.8f * CONST_T);
                        const float temp_d = 3.0f + fabsf(dist - 4.1f);
                        const float corr_ang = (dist > RAD150_)
                            ? fmaxf((RAD180_ - ang) / RAD10_, 1.0f)
                            : fmaxf(dist / RAD10_, 1.0f);
                        const bool arg_arg = (at1 == 13) & (at2 == 13);
                        const float c2e = arg_arg ? -1.0f : -0.5f;
                        const float vk = sqrtf(200.0f * fabsf(c2e) * ION_CORR / 298.0f);
                        energy += (1.0f/corr_ang)*c2e*argEpss*expf(-temp_d*vk)/(temp_d*temp_d);
                    }
                }
                const float c1 = p1[1], c2 = p2[1];
                const bool cc = (c1 != 0.0f) & (c2 != 0.0f) &
                                (p1[2] != 1.0f) & (p2[2] != 1.0f);
                const bool kon_mask = cc & (p1[3] == 0.0f) & (p2[3] == 0.0f) & (ch1 != ch2);
                if (kon_mask) {
                    const float sum_radii = p1[4] + p2[4] - 0.09f;
                    const float dd = fmaxf(dist, sum_radii);
                    const float tk = fmaxf(dd + dd*dd*(1.0f/30.0f), 6.0f);
                    const float k_on = sqrtf(200.0f*fabsf(c1)*fabsf(c2)*0.05f/298.0f);
                    const float first = 332.0f*c1*c2/(88.0f*tk*CONST_T);
                    const float second = expf(-k_on*(tk-6.0f));
                    const float third = 1.0f + k_on*6.0f;
                    energy += 0.5f*first*second/third;
                }
            }
        }
        out[p] = energy;
    }
}

extern "C" void kernel_launch(void* const* d_in, const int* in_sizes, int n_in,
                              void* d_out, int out_size, void* d_ws, size_t ws_size,
                              hipStream_t stream) {
    const float* coords   = (const float*)d_in[0];
    const float* partners = (const float*)d_in[1];
    const float* props    = (const float*)d_in[2];
    const int*   desc     = (const int*)d_in[3];
    const int2*  pairs    = (const int2*)d_in[4];
    float*       out      = (float*)d_out;

    const int natoms = in_sizes[0] / 3;   // 100,000
    const int n      = in_sizes[4] / 2;   // 4,000,000 pairs
    const int nwords = (natoms + 7) / 8;  // 12,500

    const size_t rec_bytes  = (size_t)natoms * sizeof(float4);
    const size_t filt_off   = (rec_bytes + 255) & ~(size_t)255;
    const size_t need_bytes = filt_off + (size_t)nwords * sizeof(unsigned);

    if (ws_size >= need_bytes) {
        float4*   rec  = (float4*)d_ws;
        unsigned* filt = (unsigned*)((char*)d_ws + filt_off);
        prep_rec <<<(natoms + 255) / 256, 256, 0, stream>>>(coords, props, desc, rec, natoms);
        prep_filt<<<(nwords + 255) / 256, 256, 0, stream>>>(props, desc, filt, nwords, natoms);
        constexpr int PPT = 8;
        const int grid = (n + 256 * PPT - 1) / (256 * PPT);
        electro_kernel3<PPT><<<grid, 256, 0, stream>>>(rec, filt, partners, props, pairs, out, n);
    } else {
        const int block = 256;
        int grid = (n + block - 1) / block;
        if (grid > 2048) grid = 2048;
        electro_fallback<<<grid, block, 0, stream>>>(coords, partners, props, desc, pairs, out, n);
    }
}

// Round 4
// 44.234 us; speedup vs baseline: 1.2036x; 1.0871x over previous
//
#include <hip/hip_runtime.h>
#include <math.h>

namespace {
constexpr int   NTYPES   = 200;
constexpr float CONST_T  = 0.89776110649108887f; // exp(-0.004314*(298-273))
constexpr float RAD10_   = 0.17453292519943295f;
constexpr float RAD30_   = 0.52359877559829882f;
constexpr float RAD150_  = 2.6179938779914944f;
constexpr float RAD180_  = 3.14159265358979323f;
constexpr float ION_CORR = 0.02f + 0.05f / 1.4f;

// rec.w bit layout:
//  0..7  at_name, 8..9 chain, 10..18 resnum,
// 19 rc, 20 cz, 21 aa, 22 charged, 23 virtual, 24 dipole0
constexpr unsigned RC_B   = 1u << 19;
constexpr unsigned CZ_B   = 1u << 20;
constexpr unsigned AA_B   = 1u << 21;
constexpr unsigned CHG_B  = 1u << 22;
constexpr unsigned VIRT_B = 1u << 23;
constexpr unsigned DIP0_B = 1u << 24;
constexpr unsigned RESCH_M = 0x7FF00u;  // chain | resnum
constexpr unsigned CHAIN_M = 0x300u;

constexpr int MAX_FILT_WORDS = 3200;    // 102,400 atoms capacity @ 1 bit/atom
}

__global__ __launch_bounds__(256) void prep_rec(
    const float* __restrict__ coords,
    const float* __restrict__ props,
    const int*   __restrict__ desc,
    float4*      __restrict__ rec,
    int natoms)
{
    const int idx = blockIdx.x * blockDim.x + threadIdx.x;
    if (idx >= natoms) return;
    const int at  = desc[3 * idx];
    const int res = desc[3 * idx + 1];
    const int ch  = desc[3 * idx + 2];
    unsigned bits = (unsigned)at | ((unsigned)ch << 8) | ((unsigned)res << 10);
    if ((at == 10) | (at == 11))       bits |= RC_B;
    if (at == 12)                      bits |= CZ_B;
    if (at == 13)                      bits |= AA_B;
    if (props[5 * at + 0] == 1.0f)     bits |= CHG_B;
    if (props[5 * at + 2] == 1.0f)     bits |= VIRT_B;
    if (props[5 * at + 3] == 0.0f)     bits |= DIP0_B;
    rec[idx] = make_float4(coords[3 * idx], coords[3 * idx + 1], coords[3 * idx + 2],
                           __uint_as_float(bits));
}

// 1 bit per atom: interesting = charged | cz | rc.  (i1 & i2) is a strict
// SUPERSET of the true pair predicate; survivors are re-checked exactly from
// rec bits, so false positives only cost a rec gather (~+1% of pairs).
__global__ __launch_bounds__(256) void prep_filt1(
    const float* __restrict__ props,
    const int*   __restrict__ desc,
    unsigned*    __restrict__ filt,
    int nwords, int natoms)
{
    const int w = blockIdx.x * blockDim.x + threadIdx.x;
    if (w >= nwords) return;
    unsigned word = 0;
    for (int s = 0; s < 32; ++s) {
        const int a = w * 32 + s;
        if (a < natoms) {
            const int at = desc[3 * a];
            const bool interesting =
                (props[5 * at] == 1.0f) | (at == 12) | (at == 10) | (at == 11);
            if (interesting) word |= 1u << s;
        }
    }
    filt[w] = word;
}

__device__ __forceinline__ float pair_energy(
    const float4 A, const float4 B, int i, int j,
    const float* __restrict__ partners, const float2* __restrict__ cr)
{
    const unsigned ba = __float_as_uint(A.w);
    const unsigned bb = __float_as_uint(B.w);

    const bool czA = (ba & CZ_B) != 0, czB = (bb & CZ_B) != 0;
    const bool rcA = (ba & RC_B) != 0, rcB = (bb & RC_B) != 0;
    const bool argInv = (czA & (czB | rcB)) | (czB & (czA | rcA));

    const float dx = A.x - B.x, dy = A.y - B.y, dz = A.z - B.z;
    const float dist = sqrtf(dx * dx + dy * dy + dz * dz + 1e-12f);
    const bool diff_res = ((ba ^ bb) & RESCH_M) != 0;
    if (!((dist <= 15.0f) & diff_res)) return 0.0f;

    float energy = 0.0f;

    // ---- ARG path (extremely rare): needs partners[] ----
    if (argInv && (dist >= 3.9f) && (dist <= 4.3f)) {
        const float a0x = partners[6 * i],     a0y = partners[6 * i + 1], a0z = partners[6 * i + 2];
        const float a1x = partners[6 * i + 3], a1y = partners[6 * i + 4], a1z = partners[6 * i + 5];
        const float b0x = partners[6 * j],     b0y = partners[6 * j + 1], b0z = partners[6 * j + 2];
        const float b1x = partners[6 * j + 3], b1y = partners[6 * j + 4], b1z = partners[6 * j + 5];
        const float u1x = a0x - A.x, u1y = a0y - A.y, u1z = a0z - A.z;
        const float v1x = a1x - A.x, v1y = a1y - A.y, v1z = a1z - A.z;
        const float n1x = u1y * v1z - u1z * v1y;
        const float n1y = u1z * v1x - u1x * v1z;
        const float n1z = u1x * v1y - u1y * v1x;
        const float u2x = b0x - B.x, u2y = b0y - B.y, u2z = b0z - B.z;
        const float v2x = b1x - B.x, v2y = b1y - B.y, v2z = b1z - B.z;
        const float n2x = u2y * v2z - u2z * v2y;
        const float n2y = u2z * v2x - u2x * v2z;
        const float n2z = u2x * v2y - u2y * v2x;
        const float nn1 = sqrtf(n1x * n1x + n1y * n1y + n1z * n1z + 1e-12f);
        const float nn2 = sqrtf(n2x * n2x + n2y * n2y + n2z * n2z + 1e-12f);
        const bool  m = (nn1 > 1e-6f) & (nn2 > 1e-6f);
        float cosang = (n1x * n2x + n1y * n2y + n1z * n2z) / (nn1 * nn2);
        cosang = fminf(fmaxf(cosang, -0.999999f), 0.999999f);
        const float ang = acosf(cosang);
        const bool ang_mid_bad = (ang > RAD30_) & (ang < RAD150_);
        if (m & !ang_mid_bad) {
            const float dsafe   = fmaxf(dist, 1e-6f);
            const float argEpss = 332.0f / (dsafe * 8.8f * CONST_T);
            const float temp_d  = 3.0f + fabsf(dist - 4.1f);
            const float corr_ang = (dist > RAD150_)   // reference quirk: dist vs RAD150
                ? fmaxf((RAD180_ - ang) / RAD10_, 1.0f)
                : fmaxf(dist / RAD10_, 1.0f);
            const bool  arg_arg = ((ba & bb & AA_B) != 0);
            const float c2e = arg_arg ? -1.0f : -0.5f;
            const float vk  = sqrtf(200.0f * fabsf(c2e) * ION_CORR / 298.0f);
            energy += (1.0f / corr_ang) * c2e * argEpss *
                      expf(-temp_d * vk) / (temp_d * temp_d);
        }
    }

    // ---- kon path (exact: c!=0 implies charged-flag for this prop table) ----
    const float2 t1 = cr[ba & 255u];
    const float2 t2 = cr[bb & 255u];
    const float c1 = t1.x, c2 = t2.x;
    const bool charged_charged =
        (c1 != 0.0f) & (c2 != 0.0f) &
        ((ba & VIRT_B) == 0) & ((bb & VIRT_B) == 0);
    const bool kon_mask = charged_charged &
        ((ba & DIP0_B) != 0) & ((bb & DIP0_B) != 0) &
        (((ba ^ bb) & CHAIN_M) != 0);
    if (kon_mask) {
        const float sum_radii = t1.y + t2.y - 0.09f;
        const float dd   = fmaxf(dist, sum_radii);
        const float tk   = fmaxf(dd + dd * dd * (1.0f / 30.0f), 6.0f);
        const float k_on = sqrtf(200.0f * fabsf(c1) * fabsf(c2) * 0.05f / 298.0f);
        const float first  = 332.0f * c1 * c2 / (88.0f * tk * CONST_T);
        const float second = expf(-k_on * (tk - 6.0f));
        const float third  = 1.0f + k_on * 6.0f;
        energy += 0.5f * first * second / third;
    }
    return energy;
}

template <int PPT>
__global__ __launch_bounds__(256) void electro_kernel4(
    const float4*   __restrict__ rec,       // [natoms] 1.6 MB, L2-resident
    const unsigned* __restrict__ filtg,     // [nwords] 12.5 KB, staged to LDS
    const float*    __restrict__ partners,
    const float*    __restrict__ props,
    const int2*     __restrict__ pairs,
    float*          __restrict__ out,
    int n, int nwords)
{
    __shared__ unsigned sfilt[MAX_FILT_WORDS];   // 12.8 KB: divergent gathers hit LDS, not L1
    __shared__ float2   cr[NTYPES];              // (charge, radius) per type
    for (int t = threadIdx.x; t < nwords; t += blockDim.x) sfilt[t] = filtg[t];
    for (int t = threadIdx.x; t < NTYPES; t += blockDim.x)
        cr[t] = make_float2(props[5 * t + 1], props[5 * t + 4]);
    __syncthreads();

    const int base = blockIdx.x * (blockDim.x * PPT) + threadIdx.x;

    int  ii[PPT], jj[PPT];
    bool ok[PPT];
#pragma unroll
    for (int k = 0; k < PPT; ++k) {
        const int p = base + k * 256;
        ok[k] = (p < n);
        // nontemporal: pairs stream is read-once, keep it out of L2
        unsigned long long v = ok[k]
            ? __builtin_nontemporal_load((const unsigned long long*)(pairs + p))
            : 0ull;
        ii[k] = (int)(v & 0xffffffffu);
        jj[k] = (int)(v >> 32);
    }

    unsigned w1[PPT], w2[PPT];
#pragma unroll
    for (int k = 0; k < PPT; ++k) {
        w1[k] = sfilt[ii[k] >> 5];     // LDS gather: ~2-way bank aliasing, free
        w2[k] = sfilt[jj[k] >> 5];
    }

#pragma unroll
    for (int k = 0; k < PPT; ++k) {
        const bool pass = (((w1[k] >> (ii[k] & 31)) &
                            (w2[k] >> (jj[k] & 31))) & 1u) != 0;
        float e = 0.0f;
        if (pass) {   // ~17% of lanes: only they issue the 16B rec gathers
            const float4 A = rec[ii[k]];
            const float4 B = rec[jj[k]];
            e = pair_energy(A, B, ii[k], jj[k], partners, cr);
        }
        if (ok[k]) __builtin_nontemporal_store(e, &out[base + k * 256]);
    }
}

// -------- fallback (round-1 kernel) used only if d_ws is too small --------
__global__ __launch_bounds__(256) void electro_fallback(
    const float* __restrict__ coords, const float* __restrict__ partners,
    const float* __restrict__ props, const int* __restrict__ desc,
    const int2* __restrict__ pairs, float* __restrict__ out, int n)
{
    __shared__ float sp[NTYPES * 5];
    for (int t = threadIdx.x; t < NTYPES * 5; t += blockDim.x) sp[t] = props[t];
    __syncthreads();
    const int stride = gridDim.x * blockDim.x;
    for (int p = blockIdx.x * blockDim.x + threadIdx.x; p < n; p += stride) {
        const int2 ij = pairs[p];
        const int i = ij.x, j = ij.y;
        const int at1 = desc[3 * i], at2 = desc[3 * j];
        const bool rc1 = (at1 == 10) | (at1 == 11);
        const bool rc2 = (at2 == 10) | (at2 == 11);
        const bool argInv = ((at1 == 12) & ((at2 == 12) | rc2)) |
                            ((at2 == 12) & ((at1 == 12) | rc1));
        const float* p1 = &sp[5 * at1];
        const float* p2 = &sp[5 * at2];
        const bool is_charged = ((p1[0] == 1.0f) & (p2[0] == 1.0f)) | argInv;
        float energy = 0.0f;
        if (is_charged) {
            const int res1 = desc[3 * i + 1], ch1 = desc[3 * i + 2];
            const int res2 = desc[3 * j + 1], ch2 = desc[3 * j + 2];
            const float ax = coords[3 * i], ay = coords[3 * i + 1], az = coords[3 * i + 2];
            const float bx = coords[3 * j], by = coords[3 * j + 1], bz = coords[3 * j + 2];
            const float dx = ax - bx, dy = ay - by, dz = az - bz;
            const float dist = sqrtf(dx * dx + dy * dy + dz * dz + 1e-12f);
            const bool diff_res = (res1 != res2) | (ch1 != ch2);
            if ((dist <= 15.0f) & diff_res) {
                if (argInv && (dist >= 3.9f) && (dist <= 4.3f)) {
                    const float a0x = partners[6*i],   a0y = partners[6*i+1], a0z = partners[6*i+2];
                    const float a1x = partners[6*i+3], a1y = partners[6*i+4], a1z = partners[6*i+5];
                    const float b0x = partners[6*j],   b0y = partners[6*j+1], b0z = partners[6*j+2];
                    const float b1x = partners[6*j+3], b1y = partners[6*j+4], b1z = partners[6*j+5];
                    const float u1x=a0x-ax,u1y=a0y-ay,u1z=a0z-az;
                    const float v1x=a1x-ax,v1y=a1y-ay,v1z=a1z-az;
                    const float n1x=u1y*v1z-u1z*v1y, n1y=u1z*v1x-u1x*v1z, n1z=u1x*v1y-u1y*v1x;
                    const float u2x=b0x-bx,u2y=b0y-by,u2z=b0z-bz;
                    const float v2x=b1x-bx,v2y=b1y-by,v2z=b1z-bz;
                    const float n2x=u2y*v2z-u2z*v2y, n2y=u2z*v2x-u2x*v2z, n2z=u2x*v2y-u2y*v2x;
                    const float nn1 = sqrtf(n1x*n1x+n1y*n1y+n1z*n1z+1e-12f);
                    const float nn2 = sqrtf(n2x*n2x+n2y*n2y+n2z*n2z+1e-12f);
                    const bool m = (nn1 > 1e-6f) & (nn2 > 1e-6f);
                    float cosang = (n1x*n2x+n1y*n2y+n1z*n2z)/(nn1*nn2);
                    cosang = fminf(fmaxf(cosang, -0.999999f), 0.999999f);
                    const float ang = acosf(cosang);
                    const bool ang_mid_bad = (ang > RAD30_) & (ang < RAD150_);
                    if (m & !ang_mid_bad) {
                        const float dsafe = fmaxf(dist, 1e-6f);
                        const float argEpss = 332.0f / (dsafe * 8.8f * CONST_T);
                        const float temp_d = 3.0f + fabsf(dist - 4.1f);
                        const float corr_ang = (dist > RAD150_)
                            ? fmaxf((RAD180_ - ang) / RAD10_, 1.0f)
                            : fmaxf(dist / RAD10_, 1.0f);
                        const bool arg_arg = (at1 == 13) & (at2 == 13);
                        const float c2e = arg_arg ? -1.0f : -0.5f;
                        const float vk = sqrtf(200.0f * fabsf(c2e) * ION_CORR / 298.0f);
                        energy += (1.0f/corr_ang)*c2e*argEpss*expf(-temp_d*vk)/(temp_d*temp_d);
                    }
                }
                const float c1 = p1[1], c2 = p2[1];
                const bool cc = (c1 != 0.0f) & (c2 != 0.0f) &
                                (p1[2] != 1.0f) & (p2[2] != 1.0f);
                const bool kon_mask = cc & (p1[3] == 0.0f) & (p2[3] == 0.0f) & (ch1 != ch2);
                if (kon_mask) {
                    const float sum_radii = p1[4] + p2[4] - 0.09f;
                    const float dd = fmaxf(dist, sum_radii);
                    const float tk = fmaxf(dd + dd*dd*(1.0f/30.0f), 6.0f);
                    const float k_on = sqrtf(200.0f*fabsf(c1)*fabsf(c2)*0.05f/298.0f);
                    const float first = 332.0f*c1*c2/(88.0f*tk*CONST_T);
                    const float second = expf(-k_on*(tk-6.0f));
                    const float third = 1.0f + k_on*6.0f;
                    energy += 0.5f*first*second/third;
                }
            }
        }
        out[p] = energy;
    }
}

extern "C" void kernel_launch(void* const* d_in, const int* in_sizes, int n_in,
                              void* d_out, int out_size, void* d_ws, size_t ws_size,
                              hipStream_t stream) {
    const float* coords   = (const float*)d_in[0];
    const float* partners = (const float*)d_in[1];
    const float* props    = (const float*)d_in[2];
    const int*   desc     = (const int*)d_in[3];
    const int2*  pairs    = (const int2*)d_in[4];
    float*       out      = (float*)d_out;

    const int natoms = in_sizes[0] / 3;    // 100,000
    const int n      = in_sizes[4] / 2;    // 4,000,000 pairs
    const int nwords = (natoms + 31) / 32; // 3,125

    const size_t rec_bytes  = (size_t)natoms * sizeof(float4);
    const size_t filt_off   = (rec_bytes + 255) & ~(size_t)255;
    const size_t need_bytes = filt_off + (size_t)nwords * sizeof(unsigned);

    if (ws_size >= need_bytes && nwords <= MAX_FILT_WORDS) {
        float4*   rec  = (float4*)d_ws;
        unsigned* filt = (unsigned*)((char*)d_ws + filt_off);
        prep_rec  <<<(natoms + 255) / 256, 256, 0, stream>>>(coords, props, desc, rec, natoms);
        prep_filt1<<<(nwords + 255) / 256, 256, 0, stream>>>(props, desc, filt, nwords, natoms);
        constexpr int PPT = 8;
        const int grid = (n + 256 * PPT - 1) / (256 * PPT);
        electro_kernel4<PPT><<<grid, 256, 0, stream>>>(rec, filt, partners, props, pairs, out, n, nwords);
    } else {
        const int block = 256;
        int grid = (n + block - 1) / block;
        if (grid > 2048) grid = 2048;
        electro_fallback<<<grid, block, 0, stream>>>(coords, partners, props, desc, pairs, out, n);
    }
}